// Round 5
// baseline (252.337 us; speedup 1.0000x reference)
//
#include <hip/hip_runtime.h>
#include <hip/hip_bf16.h>
#include <stdint.h>

typedef unsigned short u16;
typedef __attribute__((ext_vector_type(8))) short short8;
typedef __attribute__((ext_vector_type(4))) float f32x4;

#define BB 4
#define NN 8192
#define SS 2048
#define MTOT 32768
#define CSKIP 256
#define CLO 512
#define CIN 768
#define COUT 256

__device__ __forceinline__ u16 f2bf(float f) {
  unsigned u = __float_as_uint(f);
  u += 0x7fffu + ((u >> 16) & 1u);
  return (u16)(u >> 16);
}

__device__ __forceinline__ void gl_lds16(const void* g, void* l) {
  __builtin_amdgcn_global_load_lds(
      (const __attribute__((address_space(1))) void*)g,
      (__attribute__((address_space(3))) void*)l, 16, 0, 0);
}

// ---------------------------------------------------------------------------
// K0: weights -> bf16 transposed [n][k]
// ---------------------------------------------------------------------------
__global__ __launch_bounds__(256) void wconv_kernel(const float* __restrict__ W1,
                                                    const float* __restrict__ W2,
                                                    u16* __restrict__ W1T,
                                                    u16* __restrict__ W2T) {
  int i = blockIdx.x * 256 + threadIdx.x;
  if (i < CIN * COUT) {
    int n = i / CIN, k = i - n * CIN;
    W1T[i] = f2bf(W1[(size_t)k * COUT + n]);
  } else if (i < CIN * COUT + COUT * COUT) {
    int j = i - CIN * COUT;
    int n = j >> 8, k = j & 255;
    W2T[j] = f2bf(W2[(size_t)k * COUT + n]);
  }
}

// ---------------------------------------------------------------------------
// K1: KNN (K=3), diff-form fp32 distances (expansion form flips near-ties —
// R3 failure). lane = query, wave = candidate-partition; LDS reads are
// wave-uniform (broadcast, conflict-free).
// ---------------------------------------------------------------------------
__global__ __launch_bounds__(512) void knn_kernel(
    const float* __restrict__ xyz_hi, const float* __restrict__ xyz_lo,
    float* __restrict__ wq_g, int* __restrict__ iq_g) {
  __shared__ float4 sxyz[SS];          // 32 KB
  __shared__ float md[8][64][3];
  __shared__ int   mi[8][64][3];

  int tid = threadIdx.x;
  int blk = blockIdx.x;
  int b = blk >> 7;                    // 128 blocks per batch
  const float* xl = xyz_lo + (size_t)b * SS * 3;
  for (int j = tid; j < SS; j += 512)
    sxyz[j] = make_float4(xl[j * 3 + 0], xl[j * 3 + 1], xl[j * 3 + 2], 0.f);
  __syncthreads();

  int wave = tid >> 6, lane = tid & 63;
  int qm = blk * 64 + lane;
  float qx = xyz_hi[(size_t)qm * 3 + 0];
  float qy = xyz_hi[(size_t)qm * 3 + 1];
  float qz = xyz_hi[(size_t)qm * 3 + 2];

  float b0 = 1e30f, b1 = 1e30f, b2 = 1e30f;
  int i0 = -1, i1 = -1, i2 = -1;
  int j0 = wave * 256;
#pragma unroll 4
  for (int jj = 0; jj < 256; ++jj) {
    int j = j0 + jj;
    float4 p = sxyz[j];
    float dx = p.x - qx, dy = p.y - qy, dz = p.z - qz;
    float d = fmaf(dx, dx, fmaf(dy, dy, dz * dz));
    bool c = d < b2;
    b2 = c ? d : b2; i2 = c ? j : i2;
    bool s = b2 < b1;
    float tb = b1; b1 = s ? b2 : b1; b2 = s ? tb : b2;
    int ti = i1;   i1 = s ? i2 : i1; i2 = s ? ti : i2;
    bool v = b1 < b0;
    float ub = b0; b0 = v ? b1 : b0; b1 = v ? ub : b1;
    int ui = i0;   i0 = v ? i1 : i0; i1 = v ? ui : i1;
  }
  md[wave][lane][0] = b0; mi[wave][lane][0] = i0;
  md[wave][lane][1] = b1; mi[wave][lane][1] = i1;
  md[wave][lane][2] = b2; mi[wave][lane][2] = i2;
  __syncthreads();

  if (tid < 64) {
    int q = tid;
    float fb0 = 1e30f, fb1 = 1e30f, fb2 = 1e30f;
    int fi0 = -1, fi1 = -1, fi2 = -1;
    for (int p = 0; p < 8; ++p)
#pragma unroll
      for (int s = 0; s < 3; ++s) {
        float d = md[p][q][s]; int ix = mi[p][q][s];
        if (d < fb2 || (d == fb2 && ix < fi2)) {
          fb2 = d; fi2 = ix;
          if (fb2 < fb1 || (fb2 == fb1 && fi2 < fi1)) {
            float t = fb1; fb1 = fb2; fb2 = t; int ti = fi1; fi1 = fi2; fi2 = ti;
          }
          if (fb1 < fb0 || (fb1 == fb0 && fi1 < fi0)) {
            float t = fb0; fb0 = fb1; fb1 = t; int ti = fi0; fi0 = fi1; fi1 = ti;
          }
        }
      }
    int qm2 = blk * 64 + q;
    float d0 = sqrtf(fb0), d1 = sqrtf(fb1), d2 = sqrtf(fb2);
    float inv0 = 1.0f / (d0 + 1e-8f);
    float inv1 = 1.0f / (d1 + 1e-8f);
    float inv2 = 1.0f / (d2 + 1e-8f);
    float s = inv0 + inv1 + inv2;
    wq_g[(size_t)qm2 * 3 + 0] = inv0 / s;
    wq_g[(size_t)qm2 * 3 + 1] = inv1 / s;
    wq_g[(size_t)qm2 * 3 + 2] = inv2 / s;
    iq_g[(size_t)qm2 * 3 + 0] = fi0;
    iq_g[(size_t)qm2 * 3 + 1] = fi1;
    iq_g[(size_t)qm2 * 3 + 2] = fi2;
  }
}

// ---------------------------------------------------------------------------
// K2: fused GEMM1, software-pipelined. Tile 64x256, 256 thr (4 waves across
// N), grid 512 (2 blocks/CU). Double-buffered LDS; next-iter A-reg loads +
// B gl_lds issued right after the barrier so they fly over the MFMA phase.
// ---------------------------------------------------------------------------
__global__ __launch_bounds__(256) void gemm1_fused_kernel(
    const float* __restrict__ feat_skip, const float* __restrict__ feat_lo,
    const float* __restrict__ wq_g, const int* __restrict__ iq_g,
    const u16* __restrict__ W1T, const float* __restrict__ b1,
    u16* __restrict__ H) {
  __shared__ u16 As[2][64 * 32];   // 2 x 4 KB
  __shared__ u16 Bs[2][256 * 32];  // 2 x 16 KB
  int tid = threadIdx.x;
  int m0 = blockIdx.x << 6;
  int b = blockIdx.x >> 7;         // 128 blocks per batch
  int w = tid >> 6, lane = tid & 63;
  int quad = lane >> 4, l16 = lane & 15;

  // staging assignment: thread -> (row 0..63, 8-channel slice)
  int srow = tid >> 2;
  int sc8 = (tid & 3) << 3;
  float w0 = wq_g[(size_t)(m0 + srow) * 3 + 0];
  float w1 = wq_g[(size_t)(m0 + srow) * 3 + 1];
  float w2 = wq_g[(size_t)(m0 + srow) * 3 + 2];
  int i0 = iq_g[(size_t)(m0 + srow) * 3 + 0];
  int i1 = iq_g[(size_t)(m0 + srow) * 3 + 1];
  int i2 = iq_g[(size_t)(m0 + srow) * 3 + 2];
  const float* fl0 = feat_lo + ((size_t)b * SS + i0) * CLO + sc8;
  const float* fl1 = feat_lo + ((size_t)b * SS + i1) * CLO + sc8;
  const float* fl2 = feat_lo + ((size_t)b * SS + i2) * CLO + sc8;
  const float* fsk = feat_skip + (size_t)(m0 + srow) * CSKIP + sc8;

  float4 ra[6];
  auto loadA = [&](int kc) {
    if (kc < 8) {
      ra[0] = *(const float4*)(fsk + kc * 32);
      ra[1] = *(const float4*)(fsk + kc * 32 + 4);
    } else {
      int c = (kc - 8) * 32;
      ra[0] = *(const float4*)(fl0 + c); ra[1] = *(const float4*)(fl0 + c + 4);
      ra[2] = *(const float4*)(fl1 + c); ra[3] = *(const float4*)(fl1 + c + 4);
      ra[4] = *(const float4*)(fl2 + c); ra[5] = *(const float4*)(fl2 + c + 4);
    }
  };
  auto packA = [&](int kc, int buf) {
    float av[8];
    if (kc < 8) {
      av[0] = ra[0].x; av[1] = ra[0].y; av[2] = ra[0].z; av[3] = ra[0].w;
      av[4] = ra[1].x; av[5] = ra[1].y; av[6] = ra[1].z; av[7] = ra[1].w;
    } else {
      av[0] = fmaf(w0, ra[0].x, fmaf(w1, ra[2].x, w2 * ra[4].x));
      av[1] = fmaf(w0, ra[0].y, fmaf(w1, ra[2].y, w2 * ra[4].y));
      av[2] = fmaf(w0, ra[0].z, fmaf(w1, ra[2].z, w2 * ra[4].z));
      av[3] = fmaf(w0, ra[0].w, fmaf(w1, ra[2].w, w2 * ra[4].w));
      av[4] = fmaf(w0, ra[1].x, fmaf(w1, ra[3].x, w2 * ra[5].x));
      av[5] = fmaf(w0, ra[1].y, fmaf(w1, ra[3].y, w2 * ra[5].y));
      av[6] = fmaf(w0, ra[1].z, fmaf(w1, ra[3].z, w2 * ra[5].z));
      av[7] = fmaf(w0, ra[1].w, fmaf(w1, ra[3].w, w2 * ra[5].w));
    }
    union { __hip_bfloat162 h2[4]; uint4 u4; } pk;
#pragma unroll
    for (int c = 0; c < 4; ++c)
      pk.h2[c] = __float22bfloat162_rn(make_float2(av[2 * c], av[2 * c + 1]));
    *(uint4*)(As[buf] + srow * 32 + sc8) = pk.u4;
  };
  auto issueB = [&](int kc, int buf) {
#pragma unroll
    for (int r = 0; r < 4; ++r) {
      int u = tid + r * 256;
      int nrow = u >> 2, kb = (u & 3) << 3;
      gl_lds16(W1T + (size_t)nrow * CIN + kc * 32 + kb, (char*)Bs[buf] + u * 16);
    }
  };

  f32x4 zero = {0.f, 0.f, 0.f, 0.f};
  f32x4 acc[4][4];
#pragma unroll
  for (int tm = 0; tm < 4; ++tm)
#pragma unroll
    for (int tn = 0; tn < 4; ++tn) acc[tm][tn] = zero;

  // prologue: stage kc=0 into buffer 0
  loadA(0);
  issueB(0, 0);
  packA(0, 0);

  for (int kc = 0; kc < 24; ++kc) {
    int cur = kc & 1, nxt = cur ^ 1;
    __syncthreads();                      // buf[cur] fully staged
    bool more = (kc + 1 < 24);
    if (more) { loadA(kc + 1); issueB(kc + 1, nxt); }

    short8 af[4], bf[4];
#pragma unroll
    for (int t = 0; t < 4; ++t)
      af[t] = *(const short8*)(As[cur] + ((t * 16 + l16) * 32 + quad * 8));
#pragma unroll
    for (int t = 0; t < 4; ++t)
      bf[t] = *(const short8*)(Bs[cur] + ((w * 64 + t * 16 + l16) * 32 + quad * 8));
#pragma unroll
    for (int tm = 0; tm < 4; ++tm)
#pragma unroll
      for (int tn = 0; tn < 4; ++tn)
        acc[tm][tn] = __builtin_amdgcn_mfma_f32_16x16x32_bf16(af[tm], bf[tn], acc[tm][tn], 0, 0, 0);

    if (more) packA(kc + 1, nxt);
  }

  float bias[4];
#pragma unroll
  for (int tn = 0; tn < 4; ++tn) bias[tn] = b1[w * 64 + tn * 16 + l16];
#pragma unroll
  for (int tm = 0; tm < 4; ++tm)
#pragma unroll
    for (int tn = 0; tn < 4; ++tn) {
      int col = w * 64 + tn * 16 + l16;
#pragma unroll
      for (int r = 0; r < 4; ++r) {
        int row = m0 + tm * 16 + quad * 4 + r;
        float v = acc[tm][tn][r] + bias[tn];
        v = v > 0.f ? v : 0.f;
        H[(size_t)row * COUT + col] = f2bf(v);
      }
    }
}

// ---------------------------------------------------------------------------
// K3: GEMM2 + bias + LayerNorm, pipelined. Tile 64x256, 256 thr, grid 512.
// A and B both staged via gl_lds; next-iter issues fly over MFMA.
// ---------------------------------------------------------------------------
__global__ __launch_bounds__(256) void gemm2_ln_kernel(const u16* __restrict__ H,
                                                       const u16* __restrict__ Bt,
                                                       const float* __restrict__ b2,
                                                       const float* __restrict__ gamma,
                                                       const float* __restrict__ beta,
                                                       float* __restrict__ out) {
  __shared__ u16 As[2][64 * 32];
  __shared__ u16 Bs[2][256 * 32];
  __shared__ float red[4][64][2];
  __shared__ float stats[64][2];
  int tid = threadIdx.x;
  int m0 = blockIdx.x << 6;
  int w = tid >> 6, lane = tid & 63;
  int quad = lane >> 4, l16 = lane & 15;

  auto issueAB = [&](int kc, int buf) {
    int srow = tid >> 2, sc8 = (tid & 3) << 3;
    gl_lds16(H + (size_t)(m0 + srow) * COUT + kc * 32 + sc8,
             (char*)As[buf] + tid * 16);
#pragma unroll
    for (int r = 0; r < 4; ++r) {
      int u = tid + r * 256;
      int nrow = u >> 2, kb = (u & 3) << 3;
      gl_lds16(Bt + (size_t)nrow * COUT + kc * 32 + kb, (char*)Bs[buf] + u * 16);
    }
  };

  f32x4 zero = {0.f, 0.f, 0.f, 0.f};
  f32x4 acc[4][4];
#pragma unroll
  for (int tm = 0; tm < 4; ++tm)
#pragma unroll
    for (int tn = 0; tn < 4; ++tn) acc[tm][tn] = zero;

  issueAB(0, 0);
  for (int kc = 0; kc < 8; ++kc) {
    int cur = kc & 1, nxt = cur ^ 1;
    __syncthreads();
    if (kc + 1 < 8) issueAB(kc + 1, nxt);

    short8 af[4], bf[4];
#pragma unroll
    for (int t = 0; t < 4; ++t)
      af[t] = *(const short8*)(As[cur] + ((t * 16 + l16) * 32 + quad * 8));
#pragma unroll
    for (int t = 0; t < 4; ++t)
      bf[t] = *(const short8*)(Bs[cur] + ((w * 64 + t * 16 + l16) * 32 + quad * 8));
#pragma unroll
    for (int tm = 0; tm < 4; ++tm)
#pragma unroll
      for (int tn = 0; tn < 4; ++tn)
        acc[tm][tn] = __builtin_amdgcn_mfma_f32_16x16x32_bf16(af[tm], bf[tn], acc[tm][tn], 0, 0, 0);
  }

  float bias[4], g[4], be[4];
#pragma unroll
  for (int tn = 0; tn < 4; ++tn) {
    int col = w * 64 + tn * 16 + l16;
    bias[tn] = b2[col]; g[tn] = gamma[col]; be[tn] = beta[col];
  }
#pragma unroll
  for (int tm = 0; tm < 4; ++tm)
#pragma unroll
    for (int r = 0; r < 4; ++r) {
      float s = 0.f, sq = 0.f;
#pragma unroll
      for (int tn = 0; tn < 4; ++tn) {
        float v = acc[tm][tn][r] + bias[tn];
        acc[tm][tn][r] = v;
        s += v; sq += v * v;
      }
#pragma unroll
      for (int msk = 1; msk < 16; msk <<= 1) {
        s += __shfl_xor(s, msk);
        sq += __shfl_xor(sq, msk);
      }
      if (l16 == 0) {
        int rl = tm * 16 + quad * 4 + r;
        red[w][rl][0] = s;
        red[w][rl][1] = sq;
      }
    }
  __syncthreads();
  if (tid < 64) {
    float s = red[0][tid][0] + red[1][tid][0] + red[2][tid][0] + red[3][tid][0];
    float sq = red[0][tid][1] + red[1][tid][1] + red[2][tid][1] + red[3][tid][1];
    float mu = s * (1.f / 256.f);
    float var = sq * (1.f / 256.f) - mu * mu;
    stats[tid][0] = mu;
    stats[tid][1] = rsqrtf(var + 1e-5f);
  }
  __syncthreads();
#pragma unroll
  for (int tm = 0; tm < 4; ++tm)
#pragma unroll
    for (int r = 0; r < 4; ++r) {
      int rl = tm * 16 + quad * 4 + r;
      float mu = stats[rl][0], rstd = stats[rl][1];
#pragma unroll
      for (int tn = 0; tn < 4; ++tn) {
        int col = w * 64 + tn * 16 + l16;
        out[(size_t)(m0 + rl) * COUT + col] = (acc[tm][tn][r] - mu) * rstd * g[tn] + be[tn];
      }
    }
}

// ---------------------------------------------------------------------------
extern "C" void kernel_launch(void* const* d_in, const int* in_sizes, int n_in,
                              void* d_out, int out_size, void* d_ws, size_t ws_size,
                              hipStream_t stream) {
  const float* xyz_hi    = (const float*)d_in[0];
  const float* xyz_lo    = (const float*)d_in[1];
  const float* feat_skip = (const float*)d_in[2];
  const float* feat_lo   = (const float*)d_in[3];
  const float* W1        = (const float*)d_in[4];
  const float* b1        = (const float*)d_in[5];
  const float* W2        = (const float*)d_in[6];
  const float* b2        = (const float*)d_in[7];
  const float* gamma     = (const float*)d_in[8];
  const float* beta      = (const float*)d_in[9];
  float* out = (float*)d_out;

  char* ws = (char*)d_ws;
  u16*   H    = (u16*)ws;                                  // 16777216
  u16*   W1T  = (u16*)(ws + 16777216);                     // 393216
  u16*   W2T  = (u16*)(ws + 16777216 + 393216);            // 131072
  float* wq_g = (float*)(ws + 16777216 + 393216 + 131072); // 393216
  int*   iq_g = (int*)(ws + 16777216 + 393216 + 131072 + 393216);

  wconv_kernel<<<1024, 256, 0, stream>>>(W1, W2, W1T, W2T);
  knn_kernel<<<MTOT / 64, 512, 0, stream>>>(xyz_hi, xyz_lo, wq_g, iq_g);
  gemm1_fused_kernel<<<MTOT / 64, 256, 0, stream>>>(feat_skip, feat_lo, wq_g, iq_g, W1T, b1, H);
  gemm2_ln_kernel<<<MTOT / 64, 256, 0, stream>>>(H, W2T, b2, gamma, beta, out);
}

// Round 6
// 193.617 us; speedup vs baseline: 1.3033x; 1.3033x over previous
//
#include <hip/hip_runtime.h>
#include <hip/hip_bf16.h>
#include <stdint.h>

typedef unsigned short u16;
typedef __attribute__((ext_vector_type(8))) short short8;
typedef __attribute__((ext_vector_type(4))) float f32x4;

#define BB 4
#define NN 8192
#define SS 2048
#define MTOT 32768
#define CSKIP 256
#define CLO 512
#define CIN 768
#define COUT 256

__device__ __forceinline__ u16 f2bf(float f) {
  unsigned u = __float_as_uint(f);
  u += 0x7fffu + ((u >> 16) & 1u);
  return (u16)(u >> 16);
}

__device__ __forceinline__ void gl_lds16(const void* g, void* l) {
  __builtin_amdgcn_global_load_lds(
      (const __attribute__((address_space(1))) void*)g,
      (__attribute__((address_space(3))) void*)l, 16, 0, 0);
}

// ---------------------------------------------------------------------------
// K0: weights -> bf16 transposed [n][k]
// ---------------------------------------------------------------------------
__global__ __launch_bounds__(256) void wconv_kernel(const float* __restrict__ W1,
                                                    const float* __restrict__ W2,
                                                    u16* __restrict__ W1T,
                                                    u16* __restrict__ W2T) {
  int i = blockIdx.x * 256 + threadIdx.x;
  if (i < CIN * COUT) {
    int n = i / CIN, k = i - n * CIN;
    W1T[i] = f2bf(W1[(size_t)k * COUT + n]);
  } else if (i < CIN * COUT + COUT * COUT) {
    int j = i - CIN * COUT;
    int n = j >> 8, k = j & 255;
    W2T[j] = f2bf(W2[(size_t)k * COUT + n]);
  }
}

// ---------------------------------------------------------------------------
// K1: KNN (K=3), diff-form fp32 distances (expansion form flips near-ties —
// R3 failure). lane = query, wave = candidate-partition; LDS reads are
// wave-uniform (broadcast, conflict-free).
// ---------------------------------------------------------------------------
__global__ __launch_bounds__(512) void knn_kernel(
    const float* __restrict__ xyz_hi, const float* __restrict__ xyz_lo,
    float* __restrict__ wq_g, int* __restrict__ iq_g) {
  __shared__ float4 sxyz[SS];          // 32 KB
  __shared__ float md[8][64][3];
  __shared__ int   mi[8][64][3];

  int tid = threadIdx.x;
  int blk = blockIdx.x;
  int b = blk >> 7;                    // 128 blocks per batch
  const float* xl = xyz_lo + (size_t)b * SS * 3;
  for (int j = tid; j < SS; j += 512)
    sxyz[j] = make_float4(xl[j * 3 + 0], xl[j * 3 + 1], xl[j * 3 + 2], 0.f);
  __syncthreads();

  int wave = tid >> 6, lane = tid & 63;
  int qm = blk * 64 + lane;
  float qx = xyz_hi[(size_t)qm * 3 + 0];
  float qy = xyz_hi[(size_t)qm * 3 + 1];
  float qz = xyz_hi[(size_t)qm * 3 + 2];

  float b0 = 1e30f, b1 = 1e30f, b2 = 1e30f;
  int i0 = -1, i1 = -1, i2 = -1;
  int j0 = wave * 256;
#pragma unroll 4
  for (int jj = 0; jj < 256; ++jj) {
    int j = j0 + jj;
    float4 p = sxyz[j];
    float dx = p.x - qx, dy = p.y - qy, dz = p.z - qz;
    float d = fmaf(dx, dx, fmaf(dy, dy, dz * dz));
    bool c = d < b2;
    b2 = c ? d : b2; i2 = c ? j : i2;
    bool s = b2 < b1;
    float tb = b1; b1 = s ? b2 : b1; b2 = s ? tb : b2;
    int ti = i1;   i1 = s ? i2 : i1; i2 = s ? ti : i2;
    bool v = b1 < b0;
    float ub = b0; b0 = v ? b1 : b0; b1 = v ? ub : b1;
    int ui = i0;   i0 = v ? i1 : i0; i1 = v ? ui : i1;
  }
  md[wave][lane][0] = b0; mi[wave][lane][0] = i0;
  md[wave][lane][1] = b1; mi[wave][lane][1] = i1;
  md[wave][lane][2] = b2; mi[wave][lane][2] = i2;
  __syncthreads();

  if (tid < 64) {
    int q = tid;
    float fb0 = 1e30f, fb1 = 1e30f, fb2 = 1e30f;
    int fi0 = -1, fi1 = -1, fi2 = -1;
    for (int p = 0; p < 8; ++p)
#pragma unroll
      for (int s = 0; s < 3; ++s) {
        float d = md[p][q][s]; int ix = mi[p][q][s];
        if (d < fb2 || (d == fb2 && ix < fi2)) {
          fb2 = d; fi2 = ix;
          if (fb2 < fb1 || (fb2 == fb1 && fi2 < fi1)) {
            float t = fb1; fb1 = fb2; fb2 = t; int ti = fi1; fi1 = fi2; fi2 = ti;
          }
          if (fb1 < fb0 || (fb1 == fb0 && fi1 < fi0)) {
            float t = fb0; fb0 = fb1; fb1 = t; int ti = fi0; fi0 = fi1; fi1 = ti;
          }
        }
      }
    int qm2 = blk * 64 + q;
    float d0 = sqrtf(fb0), d1 = sqrtf(fb1), d2 = sqrtf(fb2);
    float inv0 = 1.0f / (d0 + 1e-8f);
    float inv1 = 1.0f / (d1 + 1e-8f);
    float inv2 = 1.0f / (d2 + 1e-8f);
    float s = inv0 + inv1 + inv2;
    wq_g[(size_t)qm2 * 3 + 0] = inv0 / s;
    wq_g[(size_t)qm2 * 3 + 1] = inv1 / s;
    wq_g[(size_t)qm2 * 3 + 2] = inv2 / s;
    iq_g[(size_t)qm2 * 3 + 0] = fi0;
    iq_g[(size_t)qm2 * 3 + 1] = fi1;
    iq_g[(size_t)qm2 * 3 + 2] = fi2;
  }
}

// ---------------------------------------------------------------------------
// K2: fused GEMM1. Tile 64x256, 256 thr, grid 512 (2 blocks/CU), BK=64
// (12 rounds). Single-buffer two-barrier (R4 structure — R5's reg-held
// pipeline spilled). As padded to 72 u16/row; Bs XOR-swizzled at gl_lds
// time to kill 128B-stride bank conflicts.
// ---------------------------------------------------------------------------
__global__ __launch_bounds__(256, 2) void gemm1_fused_kernel(
    const float* __restrict__ feat_skip, const float* __restrict__ feat_lo,
    const float* __restrict__ wq_g, const int* __restrict__ iq_g,
    const u16* __restrict__ W1T, const float* __restrict__ b1,
    u16* __restrict__ H) {
  __shared__ u16 As[64 * 72];    // 9 KB (padded rows)
  __shared__ u16 Bs[256 * 64];   // 32 KB (xor-swizzled chunks)
  int tid = threadIdx.x;
  int m0 = blockIdx.x << 6;
  int b = blockIdx.x >> 7;       // 128 blocks per batch
  int w = tid >> 6, lane = tid & 63;
  int quad = lane >> 4, l16 = lane & 15;

  // staging: thread -> (row 0..63, 16-channel slice)
  int srow = tid >> 2;
  int sc16 = (tid & 3) << 4;     // 0,16,32,48
  float w0 = wq_g[(size_t)(m0 + srow) * 3 + 0];
  float w1 = wq_g[(size_t)(m0 + srow) * 3 + 1];
  float w2 = wq_g[(size_t)(m0 + srow) * 3 + 2];
  int i0 = iq_g[(size_t)(m0 + srow) * 3 + 0];
  int i1 = iq_g[(size_t)(m0 + srow) * 3 + 1];
  int i2 = iq_g[(size_t)(m0 + srow) * 3 + 2];
  const float* fl0 = feat_lo + ((size_t)b * SS + i0) * CLO + sc16;
  const float* fl1 = feat_lo + ((size_t)b * SS + i1) * CLO + sc16;
  const float* fl2 = feat_lo + ((size_t)b * SS + i2) * CLO + sc16;
  const float* fsk = feat_skip + (size_t)(m0 + srow) * CSKIP + sc16;
  u16* As_dst = As + srow * 72 + sc16;

  f32x4 zero = {0.f, 0.f, 0.f, 0.f};
  f32x4 acc[4][4];
#pragma unroll
  for (int tm = 0; tm < 4; ++tm)
#pragma unroll
    for (int tn = 0; tn < 4; ++tn) acc[tm][tn] = zero;

  for (int kc = 0; kc < 12; ++kc) {
    __syncthreads();               // LDS free (previous MFMA done)
    // B staging: W1T 256x64 chunk, xor-swizzled 16B chunks
#pragma unroll
    for (int r = 0; r < 8; ++r) {
      int u = tid + r * 256;
      int nrow = u >> 3, c = u & 7;
      int cg = c ^ (nrow & 7);
      gl_lds16(W1T + (size_t)nrow * CIN + kc * 64 + cg * 8, (char*)Bs + u * 16);
    }
    // A staging: 16 channels -> bf16 -> 2x ds_write_b128
    float av[16];
    if (kc < 4) {
      const float* p = fsk + kc * 64;
#pragma unroll
      for (int c = 0; c < 4; ++c) {
        float4 x = *(const float4*)(p + c * 4);
        av[4 * c + 0] = x.x; av[4 * c + 1] = x.y;
        av[4 * c + 2] = x.z; av[4 * c + 3] = x.w;
      }
    } else {
      int c0 = (kc - 4) * 64;
#pragma unroll
      for (int c = 0; c < 4; ++c) {
        float4 a = *(const float4*)(fl0 + c0 + c * 4);
        float4 d = *(const float4*)(fl1 + c0 + c * 4);
        float4 e = *(const float4*)(fl2 + c0 + c * 4);
        av[4 * c + 0] = fmaf(w0, a.x, fmaf(w1, d.x, w2 * e.x));
        av[4 * c + 1] = fmaf(w0, a.y, fmaf(w1, d.y, w2 * e.y));
        av[4 * c + 2] = fmaf(w0, a.z, fmaf(w1, d.z, w2 * e.z));
        av[4 * c + 3] = fmaf(w0, a.w, fmaf(w1, d.w, w2 * e.w));
      }
    }
    union { __hip_bfloat162 h2[8]; uint4 u4[2]; } pk;
#pragma unroll
    for (int c = 0; c < 8; ++c)
      pk.h2[c] = __float22bfloat162_rn(make_float2(av[2 * c], av[2 * c + 1]));
    *(uint4*)As_dst = pk.u4[0];
    *(uint4*)(As_dst + 8) = pk.u4[1];
    __syncthreads();               // staging complete (vmcnt+lgkm drained)

#pragma unroll
    for (int ko = 0; ko < 2; ++ko) {
      int ck = ko * 4 + quad;
      short8 af[4], bf[4];
#pragma unroll
      for (int t = 0; t < 4; ++t)
        af[t] = *(const short8*)(As + (t * 16 + l16) * 72 + ko * 32 + quad * 8);
#pragma unroll
      for (int t = 0; t < 4; ++t) {
        int rr = w * 64 + t * 16 + l16;
        bf[t] = *(const short8*)(Bs + (rr * 8 + (ck ^ (rr & 7))) * 8);
      }
#pragma unroll
      for (int tm = 0; tm < 4; ++tm)
#pragma unroll
        for (int tn = 0; tn < 4; ++tn)
          acc[tm][tn] = __builtin_amdgcn_mfma_f32_16x16x32_bf16(af[tm], bf[tn], acc[tm][tn], 0, 0, 0);
    }
  }

  float bias[4];
#pragma unroll
  for (int tn = 0; tn < 4; ++tn) bias[tn] = b1[w * 64 + tn * 16 + l16];
#pragma unroll
  for (int tm = 0; tm < 4; ++tm)
#pragma unroll
    for (int tn = 0; tn < 4; ++tn) {
      int col = w * 64 + tn * 16 + l16;
#pragma unroll
      for (int r = 0; r < 4; ++r) {
        int row = m0 + tm * 16 + quad * 4 + r;
        float v = acc[tm][tn][r] + bias[tn];
        v = v > 0.f ? v : 0.f;
        H[(size_t)row * COUT + col] = f2bf(v);
      }
    }
}

// ---------------------------------------------------------------------------
// K3: GEMM2 + bias + LayerNorm. Tile 64x256, 256 thr, grid 512, BK=64
// (4 rounds). A and B staged via xor-swizzled gl_lds.
// ---------------------------------------------------------------------------
__global__ __launch_bounds__(256, 2) void gemm2_ln_kernel(const u16* __restrict__ H,
                                                          const u16* __restrict__ Bt,
                                                          const float* __restrict__ b2,
                                                          const float* __restrict__ gamma,
                                                          const float* __restrict__ beta,
                                                          float* __restrict__ out) {
  __shared__ u16 As[64 * 64];    // 8 KB (xor-swizzled)
  __shared__ u16 Bs[256 * 64];   // 32 KB (xor-swizzled)
  __shared__ float red[4][64][2];
  __shared__ float stats[64][2];
  int tid = threadIdx.x;
  int m0 = blockIdx.x << 6;
  int w = tid >> 6, lane = tid & 63;
  int quad = lane >> 4, l16 = lane & 15;

  f32x4 zero = {0.f, 0.f, 0.f, 0.f};
  f32x4 acc[4][4];
#pragma unroll
  for (int tm = 0; tm < 4; ++tm)
#pragma unroll
    for (int tn = 0; tn < 4; ++tn) acc[tm][tn] = zero;

  for (int kc = 0; kc < 4; ++kc) {
    __syncthreads();
#pragma unroll
    for (int r = 0; r < 2; ++r) {
      int u = tid + r * 256;
      int row = u >> 3, c = u & 7;
      int cg = c ^ (row & 7);
      gl_lds16(H + (size_t)(m0 + row) * COUT + kc * 64 + cg * 8, (char*)As + u * 16);
    }
#pragma unroll
    for (int r = 0; r < 8; ++r) {
      int u = tid + r * 256;
      int nrow = u >> 3, c = u & 7;
      int cg = c ^ (nrow & 7);
      gl_lds16(Bt + (size_t)nrow * COUT + kc * 64 + cg * 8, (char*)Bs + u * 16);
    }
    __syncthreads();

#pragma unroll
    for (int ko = 0; ko < 2; ++ko) {
      int ck = ko * 4 + quad;
      short8 af[4], bf[4];
#pragma unroll
      for (int t = 0; t < 4; ++t) {
        int ra = t * 16 + l16;
        af[t] = *(const short8*)(As + (ra * 8 + (ck ^ (ra & 7))) * 8);
      }
#pragma unroll
      for (int t = 0; t < 4; ++t) {
        int rr = w * 64 + t * 16 + l16;
        bf[t] = *(const short8*)(Bs + (rr * 8 + (ck ^ (rr & 7))) * 8);
      }
#pragma unroll
      for (int tm = 0; tm < 4; ++tm)
#pragma unroll
        for (int tn = 0; tn < 4; ++tn)
          acc[tm][tn] = __builtin_amdgcn_mfma_f32_16x16x32_bf16(af[tm], bf[tn], acc[tm][tn], 0, 0, 0);
    }
  }

  float bias[4], g[4], be[4];
#pragma unroll
  for (int tn = 0; tn < 4; ++tn) {
    int col = w * 64 + tn * 16 + l16;
    bias[tn] = b2[col]; g[tn] = gamma[col]; be[tn] = beta[col];
  }
#pragma unroll
  for (int tm = 0; tm < 4; ++tm)
#pragma unroll
    for (int r = 0; r < 4; ++r) {
      float s = 0.f, sq = 0.f;
#pragma unroll
      for (int tn = 0; tn < 4; ++tn) {
        float v = acc[tm][tn][r] + bias[tn];
        acc[tm][tn][r] = v;
        s += v; sq += v * v;
      }
#pragma unroll
      for (int msk = 1; msk < 16; msk <<= 1) {
        s += __shfl_xor(s, msk);
        sq += __shfl_xor(sq, msk);
      }
      if (l16 == 0) {
        int rl = tm * 16 + quad * 4 + r;
        red[w][rl][0] = s;
        red[w][rl][1] = sq;
      }
    }
  __syncthreads();
  if (tid < 64) {
    float s = red[0][tid][0] + red[1][tid][0] + red[2][tid][0] + red[3][tid][0];
    float sq = red[0][tid][1] + red[1][tid][1] + red[2][tid][1] + red[3][tid][1];
    float mu = s * (1.f / 256.f);
    float var = sq * (1.f / 256.f) - mu * mu;
    stats[tid][0] = mu;
    stats[tid][1] = rsqrtf(var + 1e-5f);
  }
  __syncthreads();
#pragma unroll
  for (int tm = 0; tm < 4; ++tm)
#pragma unroll
    for (int r = 0; r < 4; ++r) {
      int rl = tm * 16 + quad * 4 + r;
      float mu = stats[rl][0], rstd = stats[rl][1];
#pragma unroll
      for (int tn = 0; tn < 4; ++tn) {
        int col = w * 64 + tn * 16 + l16;
        out[(size_t)(m0 + rl) * COUT + col] = (acc[tm][tn][r] - mu) * rstd * g[tn] + be[tn];
      }
    }
}

// ---------------------------------------------------------------------------
extern "C" void kernel_launch(void* const* d_in, const int* in_sizes, int n_in,
                              void* d_out, int out_size, void* d_ws, size_t ws_size,
                              hipStream_t stream) {
  const float* xyz_hi    = (const float*)d_in[0];
  const float* xyz_lo    = (const float*)d_in[1];
  const float* feat_skip = (const float*)d_in[2];
  const float* feat_lo   = (const float*)d_in[3];
  const float* W1        = (const float*)d_in[4];
  const float* b1        = (const float*)d_in[5];
  const float* W2        = (const float*)d_in[6];
  const float* b2        = (const float*)d_in[7];
  const float* gamma     = (const float*)d_in[8];
  const float* beta      = (const float*)d_in[9];
  float* out = (float*)d_out;

  char* ws = (char*)d_ws;
  u16*   H    = (u16*)ws;                                  // 16777216
  u16*   W1T  = (u16*)(ws + 16777216);                     // 393216
  u16*   W2T  = (u16*)(ws + 16777216 + 393216);            // 131072
  float* wq_g = (float*)(ws + 16777216 + 393216 + 131072); // 393216
  int*   iq_g = (int*)(ws + 16777216 + 393216 + 131072 + 393216);

  wconv_kernel<<<1024, 256, 0, stream>>>(W1, W2, W1T, W2T);
  knn_kernel<<<MTOT / 64, 512, 0, stream>>>(xyz_hi, xyz_lo, wq_g, iq_g);
  gemm1_fused_kernel<<<MTOT / 64, 256, 0, stream>>>(feat_skip, feat_lo, wq_g, iq_g, W1T, b1, H);
  gemm2_ln_kernel<<<MTOT / 64, 256, 0, stream>>>(H, W2T, b2, gamma, beta, out);
}